// Round 1
// baseline (212.603 us; speedup 1.0000x reference)
//
#include <hip/hip_runtime.h>
#include <math.h>

#define NTOK 16384
#define KDIM 2048
#define NEXP 64
#define KC   256                 // k-chunk staged in LDS
#define NCHUNK (KDIM / KC)       // 8
#define BLOCK 512                // 8 waves
#define RPW  8                   // rows per wave
#define WPB  (BLOCK / 64)        // 8 waves per block
#define ROWS_WG (WPB * RPW)      // 64 rows per workgroup

__global__ __launch_bounds__(BLOCK, 4) void gate_main(
    const float* __restrict__ x, const float* __restrict__ gw,
    const float* __restrict__ gb, float* __restrict__ out_w,
    float* __restrict__ out_idx, float* __restrict__ ws)
{
    __shared__ float lw[KC * NEXP];          // 64 KB weight chunk
    __shared__ float red[2 * WPB * NEXP];    // 4 KB aux partials

    const int tid  = threadIdx.x;
    const int lane = tid & 63;
    const int wid  = __builtin_amdgcn_readfirstlane(tid >> 6);
    const int row0 = blockIdx.x * ROWS_WG + wid * RPW;

    float acc[RPW];
#pragma unroll
    for (int r = 0; r < RPW; ++r) acc[r] = 0.f;

    for (int c = 0; c < NCHUNK; ++c) {
        __syncthreads();  // protect previous chunk's readers
        const float4* src = (const float4*)(gw + (size_t)c * KC * NEXP);
        float4* dst = (float4*)lw;
#pragma unroll
        for (int j = 0; j < (KC * NEXP / 4) / BLOCK; ++j)
            dst[tid + j * BLOCK] = src[tid + j * BLOCK];
        __syncthreads();

        const int kbase = c * KC;
        for (int kq = 0; kq < KC; kq += 4) {
            const float w0 = lw[(kq + 0) * NEXP + lane];
            const float w1 = lw[(kq + 1) * NEXP + lane];
            const float w2 = lw[(kq + 2) * NEXP + lane];
            const float w3 = lw[(kq + 3) * NEXP + lane];
#pragma unroll
            for (int r = 0; r < RPW; ++r) {
                const float4 xv =
                    *(const float4*)(x + (size_t)(row0 + r) * KDIM + kbase + kq);
                acc[r] = fmaf(xv.x, w0, acc[r]);
                acc[r] = fmaf(xv.y, w1, acc[r]);
                acc[r] = fmaf(xv.z, w2, acc[r]);
                acc[r] = fmaf(xv.w, w3, acc[r]);
            }
        }
    }

    const float bias = gb[lane];
    float probsum = 0.f, cnt = 0.f;

#pragma unroll
    for (int r = 0; r < RPW; ++r) {
        const float logit = acc[r] + bias;

        // full softmax (for aux loss mean prob)
        float m = logit;
#pragma unroll
        for (int off = 32; off; off >>= 1) m = fmaxf(m, __shfl_xor(m, off));
        const float p = __expf(logit - m);
        float s = p;
#pragma unroll
        for (int off = 32; off; off >>= 1) s += __shfl_xor(s, off);
        probsum += p / s;

        // top-1 (ties -> lower index, matching jax.lax.top_k)
        float v1 = logit; int i1 = lane;
#pragma unroll
        for (int off = 32; off; off >>= 1) {
            const float ov = __shfl_xor(v1, off);
            const int   oi = __shfl_xor(i1, off);
            if (ov > v1 || (ov == v1 && oi < i1)) { v1 = ov; i1 = oi; }
        }
        // top-2: mask out i1
        float v2 = (lane == i1) ? -INFINITY : logit; int i2 = lane;
#pragma unroll
        for (int off = 32; off; off >>= 1) {
            const float ov = __shfl_xor(v2, off);
            const int   oi = __shfl_xor(i2, off);
            if (ov > v2 || (ov == v2 && oi < i2)) { v2 = ov; i2 = oi; }
        }

        // renormalized softmax over [v1, v2]
        const float e2   = __expf(v2 - v1);
        const float rden = 1.f / (1.f + e2);
        const float wv   = (lane == i1) ? rden : ((lane == i2) ? e2 * rden : 0.f);

        const int row = row0 + r;
        out_w[(size_t)row * NEXP + lane] = wv;
        if (lane == 0) {
            out_idx[row * 2]     = (float)i1;
            out_idx[row * 2 + 1] = (float)i2;
        }
        cnt += ((lane == i1) ? 1.f : 0.f) + ((lane == i2) ? 1.f : 0.f);
    }

    // block-level reduction of aux partials, then one atomic per expert
    red[wid * NEXP + lane]              = probsum;
    red[WPB * NEXP + wid * NEXP + lane] = cnt;
    __syncthreads();
    if (tid < 2 * NEXP) {
        const int half = tid >> 6;   // 0: probsum, 1: count
        const int e    = tid & 63;
        float v = 0.f;
#pragma unroll
        for (int w = 0; w < WPB; ++w)
            v += red[half * WPB * NEXP + w * NEXP + e];
        atomicAdd(&ws[half * NEXP + e], v);
    }
}

__global__ void gate_aux(const float* __restrict__ ws, float* __restrict__ out_aux)
{
    const int e = threadIdx.x;  // 64 threads
    const float frac = ws[NEXP + e] * (1.f / (float)(NTOK * 2));
    const float mp   = ws[e] * (1.f / (float)NTOK);
    float v = frac * mp * (float)NEXP;
#pragma unroll
    for (int off = 32; off; off >>= 1) v += __shfl_xor(v, off);
    if (e == 0) out_aux[0] = v;
}

extern "C" void kernel_launch(void* const* d_in, const int* in_sizes, int n_in,
                              void* d_out, int out_size, void* d_ws, size_t ws_size,
                              hipStream_t stream) {
    const float* x  = (const float*)d_in[0];
    const float* gw = (const float*)d_in[1];
    const float* gb = (const float*)d_in[2];

    float* out      = (float*)d_out;
    float* out_w    = out;                                  // [16384*64]
    float* out_idx  = out + (size_t)NTOK * NEXP;            // [16384*2] as floats
    float* out_aux  = out_idx + (size_t)NTOK * 2;           // [1]
    float* ws       = (float*)d_ws;                         // [128] floats

    hipMemsetAsync(ws, 0, 2 * NEXP * sizeof(float), stream);
    gate_main<<<NTOK / ROWS_WG, BLOCK, 0, stream>>>(x, gw, gb, out_w, out_idx, ws);
    gate_aux<<<1, 64, 0, stream>>>(ws, out_aux);
}

// Round 2
// 91.589 us; speedup vs baseline: 2.3213x; 2.3213x over previous
//
#include <hip/hip_runtime.h>
#include <math.h>

#define NTOK 16384
#define KDIM 2048
#define NEXP 64
#define NWAVE 16
#define BLOCK (NWAVE * 64)       // 1024 threads
#define KS (KDIM / NWAVE)        // 128 k per wave
#define XC 8                     // k per x-prefetch chunk
#define NXC (KS / XC)            // 16 chunks
#define RPAD 68                  // padded row stride for reduce buffer

typedef float f4 __attribute__((ext_vector_type(4)));
typedef float f16v __attribute__((ext_vector_type(16)));

__global__ __launch_bounds__(BLOCK, 4) void gate_main(
    const float* __restrict__ x, const float* __restrict__ gw,
    const float* __restrict__ gb, float* __restrict__ out_w,
    float* __restrict__ out_idx, float* __restrict__ ws)
{
    __shared__ float red[2 * 64 * RPAD];   // 34,816 B reduce slots
    __shared__ float meta[64 * 4];         // per-row {i1, i2, w1, w2}
    __shared__ float scnt[NEXP];           // per-expert selection counts

    const int tid  = threadIdx.x;
    const int lane = tid & 63;
    const int wid  = __builtin_amdgcn_readfirstlane(tid >> 6);
    const int row  = blockIdx.x * 64 + lane;      // lane = row

    const float* xrow  = x  + (size_t)row * KDIM + wid * KS;
    const float* wbase = gw + (size_t)wid * KS * NEXP;

    float acc[NEXP];
#pragma unroll
    for (int e = 0; e < NEXP; ++e) acc[e] = 0.f;

    // ---- GEMM phase: no barriers, per-lane x (register), uniform w ----
    f4 xa = *(const f4*)(xrow);
    f4 xb = *(const f4*)(xrow + 4);
    for (int c = 0; c < NXC; ++c) {
        const int cn = (c + 1 < NXC) ? (c + 1) : c;   // clamped prefetch
        f4 na = *(const f4*)(xrow + cn * XC);
        f4 nb = *(const f4*)(xrow + cn * XC + 4);
        const float xs[XC] = {xa.x, xa.y, xa.z, xa.w, xb.x, xb.y, xb.z, xb.w};
#pragma unroll
        for (int j = 0; j < XC; ++j) {
            const f16v* wr = (const f16v*)(wbase + (size_t)(c * XC + j) * NEXP);
#pragma unroll
            for (int q = 0; q < 4; ++q) {
                const f16v wv = wr[q];
#pragma unroll
                for (int t = 0; t < 16; ++t)
                    acc[q * 16 + t] = fmaf(xs[j], wv[t], acc[q * 16 + t]);
            }
        }
        xa = na; xb = nb;
    }

    // ---- pairwise tree reduce of 16 k-partials via 2 LDS slots ----
    for (int half = NWAVE / 2; half >= 1; half >>= 1) {
        for (int sub = 0; sub < half; sub += 2) {
            const int nslot = (half - sub < 2) ? (half - sub) : 2;
            __syncthreads();
            if (wid >= half + sub && wid < half + sub + nslot) {
                float* dst = red + (size_t)(wid - half - sub) * 64 * RPAD + lane * RPAD;
#pragma unroll
                for (int q = 0; q < 16; ++q) {
                    f4 v = {acc[q*4+0], acc[q*4+1], acc[q*4+2], acc[q*4+3]};
                    *(f4*)(dst + q * 4) = v;
                }
            }
            __syncthreads();
            if (wid >= sub && wid < sub + nslot) {
                const float* src = red + (size_t)(wid - sub) * 64 * RPAD + lane * RPAD;
#pragma unroll
                for (int q = 0; q < 16; ++q) {
                    f4 v = *(const f4*)(src + q * 4);
                    acc[q*4+0] += v.x; acc[q*4+1] += v.y;
                    acc[q*4+2] += v.z; acc[q*4+3] += v.w;
                }
            }
        }
    }

    // ---- epilogue: wave 0 owns all 64 rows, one row per lane ----
    __syncthreads();
    int i1 = 0, i2 = 0;
    if (wid == 0) {
#pragma unroll
        for (int e = 0; e < NEXP; ++e) acc[e] += gb[e];

        // top-1 then top-2; strict > keeps lowest index on ties (lax.top_k)
        float v1 = acc[0];
#pragma unroll
        for (int e = 1; e < NEXP; ++e)
            if (acc[e] > v1) { v1 = acc[e]; i1 = e; }
        float v2 = -INFINITY;
#pragma unroll
        for (int e = 0; e < NEXP; ++e)
            if (e != i1 && acc[e] > v2) { v2 = acc[e]; i2 = e; }

        // full softmax (aux loss), probs -> red slot 0
        float ssum = 0.f;
#pragma unroll
        for (int e = 0; e < NEXP; ++e) ssum += __expf(acc[e] - v1);
        const float sinv = 1.f / ssum;
        float* pr = red + (size_t)lane * RPAD;
#pragma unroll
        for (int e = 0; e < NEXP; ++e) pr[e] = __expf(acc[e] - v1) * sinv;

        // renormalized top-2 softmax weights
        const float e2 = __expf(v2 - v1);
        const float w1 = 1.f / (1.f + e2);
        f4 m = {(float)i1, (float)i2, w1, e2 * w1};
        ((f4*)meta)[lane] = m;

        // expert indices out (coalesced float2 per row)
        float2 idx2 = make_float2((float)i1, (float)i2);
        *(float2*)(out_idx + (size_t)row * 2) = idx2;

        scnt[lane] = 0.f;                       // zero before atomics below
        atomicAdd(&scnt[i1], 1.f);              // program order within wave
        atomicAdd(&scnt[i2], 1.f);
    }
    __syncthreads();
    if (wid == 0) {
        // per-expert prob column-sum over this block's 64 rows (lane = expert)
        float ps = 0.f;
#pragma unroll
        for (int r = 0; r < 64; ++r) ps += red[(size_t)r * RPAD + lane];
        atomicAdd(&ws[lane], ps);
        atomicAdd(&ws[NEXP + lane], scnt[lane]);
    }
    __syncthreads();

    // ---- gate-weight store: each wave writes 4 rows, coalesced ----
#pragma unroll
    for (int rr = 0; rr < 4; ++rr) {
        const int r = wid * 4 + rr;
        const f4 m = ((const f4*)meta)[r];      // broadcast read
        const float val = (lane == (int)m.x) ? m.z
                        : ((lane == (int)m.y) ? m.w : 0.f);
        out_w[((size_t)blockIdx.x * 64 + r) * NEXP + lane] = val;
    }
}

__global__ void gate_aux(const float* __restrict__ ws, float* __restrict__ out_aux)
{
    const int e = threadIdx.x;  // 64 threads
    const float frac = ws[NEXP + e] * (1.f / (float)(NTOK * 2));
    const float mp   = ws[e] * (1.f / (float)NTOK);
    float v = frac * mp * (float)NEXP;
#pragma unroll
    for (int off = 32; off; off >>= 1) v += __shfl_xor(v, off);
    if (e == 0) out_aux[0] = v;
}

extern "C" void kernel_launch(void* const* d_in, const int* in_sizes, int n_in,
                              void* d_out, int out_size, void* d_ws, size_t ws_size,
                              hipStream_t stream) {
    const float* x  = (const float*)d_in[0];
    const float* gw = (const float*)d_in[1];
    const float* gb = (const float*)d_in[2];

    float* out     = (float*)d_out;
    float* out_w   = out;                         // [16384*64]
    float* out_idx = out + (size_t)NTOK * NEXP;   // [16384*2] as floats
    float* out_aux = out_idx + (size_t)NTOK * 2;  // [1]
    float* ws      = (float*)d_ws;                // [128] floats

    hipMemsetAsync(ws, 0, 2 * NEXP * sizeof(float), stream);
    gate_main<<<NTOK / 64, BLOCK, 0, stream>>>(x, gw, gb, out_w, out_idx, ws);
    gate_aux<<<1, 64, 0, stream>>>(ws, out_aux);
}

// Round 3
// 81.946 us; speedup vs baseline: 2.5944x; 1.1177x over previous
//
#include <hip/hip_runtime.h>
#include <math.h>

#define NTOK 16384
#define KDIM 2048
#define NEXP 64
#define NWAVE 16
#define BLOCK (NWAVE * 64)       // 1024 threads
#define KS (KDIM / NWAVE)        // 128 k per wave
#define XC 8                     // k per x-prefetch chunk
#define NXC (KS / XC)            // 16 chunks
#define RPAD 68                  // padded row stride for reduce buffer

typedef float f4 __attribute__((ext_vector_type(4)));
typedef float f16s __attribute__((ext_vector_type(16)));

__global__ __launch_bounds__(BLOCK, 4) void gate_main(
    const float* __restrict__ x, const float* __restrict__ gw,
    const float* __restrict__ gb, float* __restrict__ out_w,
    float* __restrict__ out_idx, float* __restrict__ ws)
{
    __shared__ float red[2 * 64 * RPAD];   // 34,816 B reduce slots
    __shared__ float meta[64 * 4];         // per-row {i1, i2, w1, w2}
    __shared__ float scnt[NEXP];           // per-expert selection counts

    const int tid  = threadIdx.x;
    const int lane = tid & 63;
    const int wid  = __builtin_amdgcn_readfirstlane(tid >> 6);
    const int row  = blockIdx.x * 64 + lane;      // lane = row

    const float* xrow  = x  + (size_t)row * KDIM + wid * KS;
    const float* wbase = gw + (size_t)wid * KS * NEXP;

    float acc[NEXP];
#pragma unroll
    for (int e = 0; e < NEXP; ++e) acc[e] = 0.f;

    // ---- GEMM phase: x per-lane (VGPR), w rows via SCALAR loads (SGPR) ----
    f4 xa = *(const f4*)(xrow);
    f4 xb = *(const f4*)(xrow + 4);
    for (int c = 0; c < NXC; ++c) {
        const int cn = (c + 1 < NXC) ? (c + 1) : c;   // clamped prefetch
        f4 na = *(const f4*)(xrow + cn * XC);
        f4 nb = *(const f4*)(xrow + cn * XC + 4);
        const float xs[XC] = {xa.x, xa.y, xa.z, xa.w, xb.x, xb.y, xb.z, xb.w};
#pragma unroll
        for (int j = 0; j < XC; ++j) {
            const float* wk = wbase + (size_t)(c * XC + j) * NEXP;
            f16s wA, wB, wC, wD;
            // wave-uniform w row -> scalar data path (no TA/VMEM traffic)
            asm volatile("s_load_dwordx16 %0, %4, 0x0\n\t"
                         "s_load_dwordx16 %1, %4, 0x40\n\t"
                         "s_load_dwordx16 %2, %4, 0x80\n\t"
                         "s_load_dwordx16 %3, %4, 0xc0"
                         : "=s"(wA), "=s"(wB), "=s"(wC), "=s"(wD)
                         : "s"(wk));
            // order: loads complete before any FMA consumes them
            asm volatile("s_waitcnt lgkmcnt(0)"
                         : "+s"(wA), "+s"(wB), "+s"(wC), "+s"(wD));
#pragma unroll
            for (int t = 0; t < 16; ++t)
                acc[t]      = fmaf(xs[j], wA[t], acc[t]);
#pragma unroll
            for (int t = 0; t < 16; ++t)
                acc[16 + t] = fmaf(xs[j], wB[t], acc[16 + t]);
#pragma unroll
            for (int t = 0; t < 16; ++t)
                acc[32 + t] = fmaf(xs[j], wC[t], acc[32 + t]);
#pragma unroll
            for (int t = 0; t < 16; ++t)
                acc[48 + t] = fmaf(xs[j], wD[t], acc[48 + t]);
        }
        xa = na; xb = nb;
    }

    // ---- pairwise tree reduce of 16 k-partials via 2 LDS slots ----
    for (int half = NWAVE / 2; half >= 1; half >>= 1) {
        for (int sub = 0; sub < half; sub += 2) {
            const int nslot = (half - sub < 2) ? (half - sub) : 2;
            __syncthreads();
            if (wid >= half + sub && wid < half + sub + nslot) {
                float* dst = red + (size_t)(wid - half - sub) * 64 * RPAD + lane * RPAD;
#pragma unroll
                for (int q = 0; q < 16; ++q) {
                    f4 v = {acc[q*4+0], acc[q*4+1], acc[q*4+2], acc[q*4+3]};
                    *(f4*)(dst + q * 4) = v;
                }
            }
            __syncthreads();
            if (wid >= sub && wid < sub + nslot) {
                const float* src = red + (size_t)(wid - sub) * 64 * RPAD + lane * RPAD;
#pragma unroll
                for (int q = 0; q < 16; ++q) {
                    f4 v = *(const f4*)(src + q * 4);
                    acc[q*4+0] += v.x; acc[q*4+1] += v.y;
                    acc[q*4+2] += v.z; acc[q*4+3] += v.w;
                }
            }
        }
    }

    // ---- epilogue: wave 0 owns all 64 rows, one row per lane ----
    __syncthreads();
    int i1 = 0, i2 = 0;
    if (wid == 0) {
#pragma unroll
        for (int e = 0; e < NEXP; ++e) acc[e] += gb[e];

        // top-1 then top-2; strict > keeps lowest index on ties (lax.top_k)
        float v1 = acc[0];
#pragma unroll
        for (int e = 1; e < NEXP; ++e)
            if (acc[e] > v1) { v1 = acc[e]; i1 = e; }
        float v2 = -INFINITY;
#pragma unroll
        for (int e = 0; e < NEXP; ++e)
            if (e != i1 && acc[e] > v2) { v2 = acc[e]; i2 = e; }

        // full softmax (aux loss), probs -> red slot 0
        float ssum = 0.f;
#pragma unroll
        for (int e = 0; e < NEXP; ++e) ssum += __expf(acc[e] - v1);
        const float sinv = 1.f / ssum;
        float* pr = red + (size_t)lane * RPAD;
#pragma unroll
        for (int e = 0; e < NEXP; ++e) pr[e] = __expf(acc[e] - v1) * sinv;

        // renormalized top-2 softmax weights
        const float e2 = __expf(v2 - v1);
        const float w1 = 1.f / (1.f + e2);
        f4 m = {(float)i1, (float)i2, w1, e2 * w1};
        ((f4*)meta)[lane] = m;

        // expert indices out (coalesced float2 per row)
        float2 idx2 = make_float2((float)i1, (float)i2);
        *(float2*)(out_idx + (size_t)row * 2) = idx2;

        scnt[lane] = 0.f;                       // zero before atomics below
        atomicAdd(&scnt[i1], 1.f);
        atomicAdd(&scnt[i2], 1.f);
    }
    __syncthreads();
    if (wid == 0) {
        // per-expert prob column-sum over this block's 64 rows (lane = expert)
        float ps = 0.f;
#pragma unroll
        for (int r = 0; r < 64; ++r) ps += red[(size_t)r * RPAD + lane];
        atomicAdd(&ws[lane], ps);
        atomicAdd(&ws[NEXP + lane], scnt[lane]);
    }
    __syncthreads();

    // ---- gate-weight store: each wave writes 4 rows, coalesced ----
#pragma unroll
    for (int rr = 0; rr < 4; ++rr) {
        const int r = wid * 4 + rr;
        const f4 m = ((const f4*)meta)[r];      // broadcast read
        const float val = (lane == (int)m.x) ? m.z
                        : ((lane == (int)m.y) ? m.w : 0.f);
        out_w[((size_t)blockIdx.x * 64 + r) * NEXP + lane] = val;
    }
}

__global__ void gate_aux(const float* __restrict__ ws, float* __restrict__ out_aux)
{
    const int e = threadIdx.x;  // 64 threads
    const float frac = ws[NEXP + e] * (1.f / (float)(NTOK * 2));
    const float mp   = ws[e] * (1.f / (float)NTOK);
    float v = frac * mp * (float)NEXP;
#pragma unroll
    for (int off = 32; off; off >>= 1) v += __shfl_xor(v, off);
    if (e == 0) out_aux[0] = v;
}

extern "C" void kernel_launch(void* const* d_in, const int* in_sizes, int n_in,
                              void* d_out, int out_size, void* d_ws, size_t ws_size,
                              hipStream_t stream) {
    const float* x  = (const float*)d_in[0];
    const float* gw = (const float*)d_in[1];
    const float* gb = (const float*)d_in[2];

    float* out     = (float*)d_out;
    float* out_w   = out;                         // [16384*64]
    float* out_idx = out + (size_t)NTOK * NEXP;   // [16384*2] as floats
    float* out_aux = out_idx + (size_t)NTOK * 2;  // [1]
    float* ws      = (float*)d_ws;                // [128] floats

    hipMemsetAsync(ws, 0, 2 * NEXP * sizeof(float), stream);
    gate_main<<<NTOK / 64, BLOCK, 0, stream>>>(x, gw, gb, out_w, out_idx, ws);
    gate_aux<<<1, 64, 0, stream>>>(ws, out_aux);
}